// Round 6
// baseline (408.696 us; speedup 1.0000x reference)
//
#include <hip/hip_runtime.h>

// TGV prox primal-dual, 30 iterations on (3,512,512) fp32.
// TWO ITERATIONS FUSED PER LAUNCH (15 launches). Rationale (R4/R5 ladder):
// traffic cut 1.65x -> -3.6%; occupancy x2 -> -3.2%  => per-iteration time is
// dominated by a fixed per-dispatch cost (gap + ramp + L2 drain). Halving the
// dispatch count attacks exactly that term.
// Per block (64x16 tile): staged u^{k-1} fp16 -> su; then 4 phases:
//   A: stage-1 iter k   rows -3..18, strips -4..64 -> sbA (xbar/rbar),
//      sbB (xnew/rnew, rows -1..16)
//   B: stage-2 iter k   rows -2..17 -> u^k IN PLACE into su (masked to image,
//      preserving zero-padding semantics; safe: stage-2 reads u-old only at
//      its own point)
//   C: stage-1 iter k+1 rows -1..16 (inputs sbB + su=u^k) -> global x/r writes
//      + xbar^{k+1} stashed in registers, written to sbA after ONE barrier
//      (sbA is WAR-hazarded against B; no mid-loop barriers)
//   D: stage-2 iter k+1 on interior -> global u writes
// All stale/garbage halo cells (uncomputed sbA/su columns, OOI rows) feed only
// outputs that are unused or killed by the im0/imH/jm0/jmW boundary gates
// (traced per phase). Compute is only ~1.15x of two unfused iters.
// State fp16 (r,u) / fp32 (x2) as verified in R4/R5 (absmax 0.0156 vs 0.0813).
// R3 note: cooperative grid.sync costs ~200us/iter on 8 XCDs -> launches ARE
// the cheapest grid barrier; fusing work per launch is the only way down.

#define H 512
#define W 512
#define C 3
#define HW (H * W)
#define CHW (C * H * W)

#define TW 64
#define TH 16

#define TAU     0.01f
#define LAM2    0.15f
#define RHO     1.99f
#define SIGMA   1.3888888888888888f   /* 1/TAU/72 */
#define INV_TL1 1000.0f               /* 1/(TAU*LAM1) */
#define INV_1PT (1.0f / 1.01f)        /* 1/(1+TAU) */

typedef _Float16 f16;
typedef __attribute__((ext_vector_type(4))) _Float16 h4;

// fp16 state plane order within an h-buffer: 0=r0 1=r1 2..5=u0..u3
#define HP_R0 0
#define HP_R1 1
#define HP_U  2

template <int MODE> // 0 = first pair (iters 1,2), 1 = middle, 2 = last pair (29,30)
__global__ __launch_bounds__(256)
void fused2(const float* __restrict__ y,
            const float* __restrict__ srcX,
            const f16*   __restrict__ srcH,
            float*       __restrict__ dstX,
            f16*         __restrict__ dstH,
            float*       __restrict__ outp)
{
    // su: u state, rows gi-i0 in [-4,19] (lrU=rr+4), cols gj-j0 in [-8,71] (lcU=col+8)
    __shared__ f16   su[4][24][80];          // 15.4 KB
    // sbA: xbar/rbar, rows [-3,18] (lrA=rr+3), cols [-8,71] (lcA=col+8)
    __shared__ float sbA[3][22][80];         // 21.1 KB
    // sbB: xnew/rnew of iter k, rows [-1,16] (lrB=rr+1), cols [-4,71] (lcB=col+4)
    __shared__ float sbB[3][18][76];         // 16.0 KB

    const int tid = threadIdx.x;
    const int c   = blockIdx.z;
    const int i0  = blockIdx.y * TH;
    const int j0  = blockIdx.x * TW;
    const int cb  = c * HW;

    // ---- stage u^{k-1} into su (zeros for MODE 0) ----
    for (int t = tid; t < 4 * 24 * 20; t += 256) {
        const int pl  = t / (24 * 20);
        const int rm  = t - pl * (24 * 20);
        const int row = rm / 20;
        const int kk  = rm - row * 20;
        const int gi  = i0 + row - 4;
        const int gj  = j0 + 4 * kk - 8;
        h4 v = {};
        if (MODE != 0 && (unsigned)gi < H) {
            const f16* p = srcH + (HP_U + pl) * CHW + cb + gi * W;
            if (gj >= 0 && gj + 3 < W) {
                v = *(const h4*)(p + gj);
            } else {
                if ((unsigned)(gj + 0) < W) v[0] = p[gj + 0];
                if ((unsigned)(gj + 1) < W) v[1] = p[gj + 1];
                if ((unsigned)(gj + 2) < W) v[2] = p[gj + 2];
                if ((unsigned)(gj + 3) < W) v[3] = p[gj + 3];
            }
        }
        *(h4*)&su[pl][row][4 * kk] = v;
    }
    __syncthreads();

    // ---- t-term gather from su (u at current iterate) ----
    auto tgather = [&](int rr, int s, int gi, int gjb,
                       float* t0c, float* t1c, float* t0n, float* t1w) {
        const int lr = rr + 4;
        const int lc = s + 8;
        h4 v;
        float u0n[4], u0c[4], u0s[4], u1n[5], u1c[5], u2r[6], u3n[5], u3c[5];
        v = *(const h4*)&su[0][lr - 1][lc]; u0n[0]=v[0]; u0n[1]=v[1]; u0n[2]=v[2]; u0n[3]=v[3];
        v = *(const h4*)&su[0][lr    ][lc]; u0c[0]=v[0]; u0c[1]=v[1]; u0c[2]=v[2]; u0c[3]=v[3];
        v = *(const h4*)&su[0][lr + 1][lc]; u0s[0]=v[0]; u0s[1]=v[1]; u0s[2]=v[2]; u0s[3]=v[3];
        v = *(const h4*)&su[1][lr - 1][lc]; u1n[0]=v[0]; u1n[1]=v[1]; u1n[2]=v[2]; u1n[3]=v[3];
        u1n[4] = su[1][lr - 1][lc + 4];
        v = *(const h4*)&su[1][lr    ][lc]; u1c[0]=v[0]; u1c[1]=v[1]; u1c[2]=v[2]; u1c[3]=v[3];
        u1c[4] = su[1][lr][lc + 4];
        u2r[0] = su[2][lr][lc - 1];
        v = *(const h4*)&su[2][lr][lc]; u2r[1]=v[0]; u2r[2]=v[1]; u2r[3]=v[2]; u2r[4]=v[3];
        u2r[5] = su[2][lr][lc + 4];
        u3n[0] = su[3][lr - 1][lc - 1];
        v = *(const h4*)&su[3][lr - 1][lc]; u3n[1]=v[0]; u3n[2]=v[1]; u3n[3]=v[2]; u3n[4]=v[3];
        u3c[0] = su[3][lr][lc - 1];
        v = *(const h4*)&su[3][lr][lc]; u3c[1]=v[0]; u3c[2]=v[1]; u3c[3]=v[2]; u3c[4]=v[3];

        const bool im0 = gi > 0, imHl = gi < H - 1;
        #pragma unroll
        for (int e = 0; e < 4; ++e) {
            const int gj = gjb + e;
            const bool jm0 = gj > 0;
            t0c[e] = TAU * (u0c[e] - u0s[e] + (jm0 ? u1c[e] : 0.f) - u1c[e + 1]);
            t1c[e] = TAU * (u2r[e + 1] - u2r[e + 2] + u3n[e + 1] - (imHl ? u3c[e + 1] : 0.f));
            t0n[e] = im0 ? TAU * (u0n[e] - u0c[e] + (jm0 ? u1n[e] : 0.f) - u1n[e + 1]) : 0.f;
            t1w[e] = jm0 ? TAU * (u2r[e] - u2r[e + 1] + u3n[e] - (imHl ? u3c[e] : 0.f)) : 0.f;
        }
    };

    // ---- stage-1 core ----
    auto s1core = [&](int gi, int gjb,
                      const float* yv, const float* x2c, const float* r0c, const float* r1c,
                      const float* t0c, const float* t1c, const float* t0n, const float* t1w,
                      float* xb, float* rb0, float* rb1,
                      float* xnew, float* rn0, float* rn1) {
        const bool imH = gi < H - 1;
        #pragma unroll
        for (int e = 0; e < 4; ++e) {
            const int gj = gjb + e;
            const bool jmW = gj < W - 1;
            const float nT  = t0n[e] - (imH ? t0c[e] : 0.f) + t1w[e] - (jmW ? t1c[e] : 0.f);
            const float xv  = (x2c[e] - nT + TAU * yv[e]) * INV_1PT;
            xb[e] = 2.f * xv - x2c[e];
            const float rp0 = r0c[e] + t0c[e];
            const float rp1 = r1c[e] + t1c[e];
            const float nrm = sqrtf(rp0 * rp0 + rp1 * rp1);
            const float f   = 1.f - 1.f / fmaxf(nrm * INV_TL1, 1.f);
            const float rv0 = rp0 * f, rv1 = rp1 * f;
            rb0[e]  = 2.f * rv0 - r0c[e];
            rb1[e]  = 2.f * rv1 - r1c[e];
            xnew[e] = x2c[e] + RHO * (xv - x2c[e]);
            rn0[e]  = r0c[e] + RHO * (rv0 - r0c[e]);
            rn1[e]  = r1c[e] + RHO * (rv1 - r1c[e]);
        }
    };

    // ---- stage-2 core: reads sbA (+u-old from su), returns un ----
    auto s2core = [&](int rr, int s, float* un0, float* un1, float* un2, float* un3) {
        const int gi  = i0 + rr;
        const int gjb = j0 + s;
        const int lr  = rr + 3;
        const int lc  = s + 8;
        float4 v;
        float xA[6], xS[6], xN[4], r0C[5], r0N[4], r1C[5], r1S[4];
        xA[0] = sbA[0][lr][lc - 1];
        v = *(const float4*)&sbA[0][lr][lc]; xA[1]=v.x; xA[2]=v.y; xA[3]=v.z; xA[4]=v.w;
        xA[5] = sbA[0][lr][lc + 4];
        xS[0] = sbA[0][lr + 1][lc - 1];
        v = *(const float4*)&sbA[0][lr + 1][lc]; xS[1]=v.x; xS[2]=v.y; xS[3]=v.z; xS[4]=v.w;
        xS[5] = sbA[0][lr + 1][lc + 4];
        v = *(const float4*)&sbA[0][lr - 1][lc]; xN[0]=v.x; xN[1]=v.y; xN[2]=v.z; xN[3]=v.w;
        r0C[0] = sbA[1][lr][lc - 1];
        v = *(const float4*)&sbA[1][lr][lc]; r0C[1]=v.x; r0C[2]=v.y; r0C[3]=v.z; r0C[4]=v.w;
        v = *(const float4*)&sbA[1][lr - 1][lc]; r0N[0]=v.x; r0N[1]=v.y; r0N[2]=v.z; r0N[3]=v.w;
        r1C[0] = sbA[2][lr][lc - 1];
        v = *(const float4*)&sbA[2][lr][lc]; r1C[1]=v.x; r1C[2]=v.y; r1C[3]=v.z; r1C[4]=v.w;
        v = *(const float4*)&sbA[2][lr + 1][lc]; r1S[0]=v.x; r1S[1]=v.y; r1S[2]=v.z; r1S[3]=v.w;

        h4 hv;
        float u0o[4], u1o[4], u2o[4], u3o[4];
        const int lru = rr + 4, lcu = s + 8;
        hv = *(const h4*)&su[0][lru][lcu]; u0o[0]=hv[0]; u0o[1]=hv[1]; u0o[2]=hv[2]; u0o[3]=hv[3];
        hv = *(const h4*)&su[1][lru][lcu]; u1o[0]=hv[0]; u1o[1]=hv[1]; u1o[2]=hv[2]; u1o[3]=hv[3];
        hv = *(const h4*)&su[2][lru][lcu]; u2o[0]=hv[0]; u2o[1]=hv[1]; u2o[2]=hv[2]; u2o[3]=hv[3];
        hv = *(const h4*)&su[3][lru][lcu]; u3o[0]=hv[0]; u3o[1]=hv[1]; u3o[2]=hv[2]; u3o[3]=hv[3];

        const bool im0 = gi > 0, imH = gi < H - 1;
        #pragma unroll
        for (int e = 0; e < 4; ++e) {
            const int gj = gjb + e;
            const bool jm0 = gj > 0, jmW = gj < W - 1;
            const float xC = xA[e + 1], xE = xA[e + 2], xW_ = xA[e];
            const float I0c = (imH ? xS[e + 1] - xC : 0.f) - r0C[e + 1];
            const float I0n = im0 ? (xC - xN[e] - r0N[e]) : 0.f;
            const float I0w = jm0 ? ((imH ? xS[e] - xW_ : 0.f) - r0C[e]) : 0.f;
            const float I1c = (jmW ? xE - xC : 0.f) - r1C[e + 1];
            const float I1w = jm0 ? (xC - xW_ - r1C[e]) : 0.f;
            const float I1s = imH ? ((jmW ? xS[e + 2] - xS[e + 1] : 0.f) - r1S[e]) : 0.f;
            const float g0 = I0c - I0n;
            const float g1 = jm0 ? (I0c - I0w) : 0.f;
            const float g2 = I1c - I1w;
            const float g3 = imH ? (I1s - I1c) : 0.f;
            const float up0 = u0o[e] + SIGMA * g0;
            const float up1 = u1o[e] + SIGMA * g1;
            const float up2 = u2o[e] + SIGMA * g2;
            const float up3 = u3o[e] + SIGMA * g3;
            const float nrm = sqrtf(up0 * up0 + up1 * up1 + up2 * up2 + up3 * up3);
            const float inv = 1.f / fmaxf(nrm * (1.0f / LAM2), 1.f);
            un0[e] = u0o[e] + RHO * (up0 * inv - u0o[e]);
            un1[e] = u1o[e] + RHO * (up1 * inv - u1o[e]);
            un2[e] = u2o[e] + RHO * (up2 * inv - u2o[e]);
            un3[e] = u3o[e] + RHO * (up3 * inv - u3o[e]);
        }
    };

    // ---- phase A: stage-1 of iter k on rows -3..18, strips -4..64 ----
    for (int idx = tid; idx < 22 * 18; idx += 256) {
        const int rw = idx / 18;
        const int rr = rw - 3;
        const int s  = 4 * (idx - rw * 18) - 4;
        const int gi = i0 + rr, gjb = j0 + s;
        const bool row_ok = (unsigned)gi < H;

        float yv[4], x2c[4], r0c[4], r1c[4];
        if (row_ok && gjb >= 0 && gjb + 3 < W) {
            const int p = cb + gi * W + gjb;
            *(float4*)yv = *(const float4*)(y + p);
            if (MODE != 0) {
                *(float4*)x2c = *(const float4*)(srcX + p);
                h4 h0 = *(const h4*)(srcH + HP_R0 * CHW + p);
                h4 h1 = *(const h4*)(srcH + HP_R1 * CHW + p);
                #pragma unroll
                for (int e = 0; e < 4; ++e) { r0c[e] = (float)h0[e]; r1c[e] = (float)h1[e]; }
            }
        } else {
            #pragma unroll
            for (int e = 0; e < 4; ++e) {
                const int gj = gjb + e;
                const bool ok = row_ok && ((unsigned)gj < W);
                const int p = cb + gi * W + gj;
                yv[e] = ok ? y[p] : 0.f;
                if (MODE != 0) {
                    x2c[e] = ok ? srcX[p] : 0.f;
                    r0c[e] = ok ? (float)srcH[HP_R0 * CHW + p] : 0.f;
                    r1c[e] = ok ? (float)srcH[HP_R1 * CHW + p] : 0.f;
                }
            }
        }
        float t0c[4], t1c[4], t0n[4], t1w[4];
        if (MODE == 0) {
            #pragma unroll
            for (int e = 0; e < 4; ++e) {
                x2c[e] = yv[e]; r0c[e] = 0.f; r1c[e] = 0.f;
                t0c[e] = t1c[e] = t0n[e] = t1w[e] = 0.f;
            }
        } else {
            tgather(rr, s, gi, gjb, t0c, t1c, t0n, t1w);
        }

        float xb[4], rb0[4], rb1[4], xn[4], rn0[4], rn1[4];
        s1core(gi, gjb, yv, x2c, r0c, r1c, t0c, t1c, t0n, t1w, xb, rb0, rb1, xn, rn0, rn1);

        *(float4*)&sbA[0][rr + 3][s + 8] = *(float4*)xb;
        *(float4*)&sbA[1][rr + 3][s + 8] = *(float4*)rb0;
        *(float4*)&sbA[2][rr + 3][s + 8] = *(float4*)rb1;
        if (rr >= -1 && rr <= 16) {
            *(float4*)&sbB[0][rr + 1][s + 4] = *(float4*)xn;
            *(float4*)&sbB[1][rr + 1][s + 4] = *(float4*)rn0;
            *(float4*)&sbB[2][rr + 1][s + 4] = *(float4*)rn1;
        }
    }
    __syncthreads();

    // ---- phase B: stage-2 of iter k on rows -2..17 -> u^k in place (masked) ----
    for (int idx = tid; idx < 20 * 18; idx += 256) {
        const int rw = idx / 18;
        const int rr = rw - 2;
        const int s  = 4 * (idx - rw * 18) - 4;
        const int gi = i0 + rr, gjb = j0 + s;

        float un0[4], un1[4], un2[4], un3[4];
        s2core(rr, s, un0, un1, un2, un3);

        if ((unsigned)gi < H) {
            const int lru = rr + 4, lcu = s + 8;
            if (gjb >= 0 && gjb + 3 < W) {
                h4 o0, o1, o2, o3;
                #pragma unroll
                for (int e = 0; e < 4; ++e) {
                    o0[e] = (f16)un0[e]; o1[e] = (f16)un1[e];
                    o2[e] = (f16)un2[e]; o3[e] = (f16)un3[e];
                }
                *(h4*)&su[0][lru][lcu] = o0;
                *(h4*)&su[1][lru][lcu] = o1;
                *(h4*)&su[2][lru][lcu] = o2;
                *(h4*)&su[3][lru][lcu] = o3;
            } else {
                #pragma unroll
                for (int e = 0; e < 4; ++e) {
                    if ((unsigned)(gjb + e) < W) {
                        su[0][lru][lcu + e] = (f16)un0[e];
                        su[1][lru][lcu + e] = (f16)un1[e];
                        su[2][lru][lcu + e] = (f16)un2[e];
                        su[3][lru][lcu + e] = (f16)un3[e];
                    }
                }
            }
        }
    }
    __syncthreads();

    // ---- phase C: stage-1 of iter k+1 on rows -1..16 (inputs sbB + su=u^k).
    //      Global x/r writes issue immediately; xbar/rbar stashed in registers
    //      (<=2 strips/thread) and written to sbA only after the barrier
    //      (WAR vs phase-B readers). ----
    float cxb[2][4], crb0[2][4], crb1[2][4];
    int   cidx[2] = { -1, -1 };
    {
        int slot = 0;
        for (int idx = tid; idx < 18 * 18; idx += 256, ++slot) {
            const int rw = idx / 18;
            const int rr = rw - 1;
            const int s  = 4 * (idx - rw * 18) - 4;
            const int gi = i0 + rr, gjb = j0 + s;
            const bool row_ok = (unsigned)gi < H;

            float yv[4];
            if (row_ok && gjb >= 0 && gjb + 3 < W) {
                *(float4*)yv = *(const float4*)(y + cb + gi * W + gjb);
            } else {
                #pragma unroll
                for (int e = 0; e < 4; ++e)
                    yv[e] = (row_ok && (unsigned)(gjb + e) < W) ? y[cb + gi * W + gjb + e] : 0.f;
            }
            float x2c[4], r0c[4], r1c[4];
            *(float4*)x2c = *(const float4*)&sbB[0][rr + 1][s + 4];
            *(float4*)r0c = *(const float4*)&sbB[1][rr + 1][s + 4];
            *(float4*)r1c = *(const float4*)&sbB[2][rr + 1][s + 4];

            float t0c[4], t1c[4], t0n[4], t1w[4];
            tgather(rr, s, gi, gjb, t0c, t1c, t0n, t1w);

            float xb[4], rb0[4], rb1[4], xn[4], rn0[4], rn1[4];
            s1core(gi, gjb, yv, x2c, r0c, r1c, t0c, t1c, t0n, t1w, xb, rb0, rb1, xn, rn0, rn1);

            if ((unsigned)rr < 16 && (unsigned)s < 64) { // fully-interior strip
                const int p = cb + gi * W + gjb;
                if (MODE == 2) {
                    *(float4*)(outp + p) = *(float4*)xn;
                    *(float4*)(outp + CHW + 2 * p)     = make_float4(rn0[0], rn1[0], rn0[1], rn1[1]);
                    *(float4*)(outp + CHW + 2 * p + 4) = make_float4(rn0[2], rn1[2], rn0[3], rn1[3]);
                } else {
                    *(float4*)(dstX + p) = *(float4*)xn;
                    h4 h0, h1;
                    #pragma unroll
                    for (int e = 0; e < 4; ++e) { h0[e] = (f16)rn0[e]; h1[e] = (f16)rn1[e]; }
                    *(h4*)(dstH + HP_R0 * CHW + p) = h0;
                    *(h4*)(dstH + HP_R1 * CHW + p) = h1;
                }
            }
            cidx[slot] = idx;
            #pragma unroll
            for (int e = 0; e < 4; ++e) {
                cxb[slot][e] = xb[e]; crb0[slot][e] = rb0[e]; crb1[slot][e] = rb1[e];
            }
        }
    }
    __syncthreads(); // all phase-B/C sbA reads done; safe to overwrite sbA

    #pragma unroll
    for (int slot = 0; slot < 2; ++slot) {
        if (cidx[slot] >= 0) {
            const int idx = cidx[slot];
            const int rw = idx / 18;
            const int rr = rw - 1;
            const int s  = 4 * (idx - rw * 18) - 4;
            *(float4*)&sbA[0][rr + 3][s + 8] = *(float4*)cxb[slot];
            *(float4*)&sbA[1][rr + 3][s + 8] = *(float4*)crb0[slot];
            *(float4*)&sbA[2][rr + 3][s + 8] = *(float4*)crb1[slot];
        }
    }
    __syncthreads();

    // ---- phase D: stage-2 of iter k+1 on interior -> global u ----
    {
        const int rr = tid >> 4;
        const int s  = 4 * (tid & 15);
        float un0[4], un1[4], un2[4], un3[4];
        s2core(rr, s, un0, un1, un2, un3);

        const int p = cb + (i0 + rr) * W + (j0 + s);
        if (MODE == 2) {
            #pragma unroll
            for (int e = 0; e < 4; ++e)
                *(float4*)(outp + 3 * CHW + 4 * (p + e)) =
                    make_float4(un0[e], un1[e], un2[e], un3[e]);
        } else {
            h4 o0, o1, o2, o3;
            #pragma unroll
            for (int e = 0; e < 4; ++e) {
                o0[e] = (f16)un0[e]; o1[e] = (f16)un1[e];
                o2[e] = (f16)un2[e]; o3[e] = (f16)un3[e];
            }
            *(h4*)(dstH + (HP_U + 0) * CHW + p) = o0;
            *(h4*)(dstH + (HP_U + 1) * CHW + p) = o1;
            *(h4*)(dstH + (HP_U + 2) * CHW + p) = o2;
            *(h4*)(dstH + (HP_U + 3) * CHW + p) = o3;
        }
    }
}

extern "C" void kernel_launch(void* const* d_in, const int* in_sizes, int n_in,
                              void* d_out, int out_size, void* d_ws, size_t ws_size,
                              hipStream_t stream) {
    const float* y = (const float*)d_in[0];
    float* out = (float*)d_out;

    // ws layout: x2 fp32 buf0 | x2 fp32 buf1 | h-buf0 (6*CHW f16) | h-buf1
    float* x0 = (float*)d_ws;
    float* x1 = x0 + CHW;
    f16*   h0 = (f16*)(x1 + CHW);
    f16*   h1 = h0 + 6 * CHW;

    dim3 blk(256, 1, 1);
    dim3 grd(W / TW, H / TH, C);    // (8, 32, 3) = 768 blocks = 3/CU, 1 round

    // 15 fused launches: pairs (1,2),(3,4),...,(29,30)
    fused2<0><<<grd, blk, 0, stream>>>(y, nullptr, nullptr, x0, h0, nullptr);
    for (int i = 1; i < 14; ++i) {
        const bool odd = (i & 1);
        float* sx = odd ? x0 : x1;  f16* sh = odd ? h0 : h1;
        float* dx = odd ? x1 : x0;  f16* dh = odd ? h1 : h0;
        fused2<1><<<grd, blk, 0, stream>>>(y, sx, sh, dx, dh, nullptr);
    }
    fused2<2><<<grd, blk, 0, stream>>>(y, x1, h1, nullptr, nullptr, out);
}